// Round 1
// baseline (189.667 us; speedup 1.0000x reference)
//
#include <hip/hip_runtime.h>
#include <hip/hip_bf16.h>
#include <math.h>

#define MDIM 8192
#define NDIM 4096
#define KDIM 128

typedef __bf16 bf16x8 __attribute__((ext_vector_type(8)));
typedef float f32x4 __attribute__((ext_vector_type(4)));

__device__ __forceinline__ unsigned short f32_to_bf16_rne(float f) {
  unsigned int u = __float_as_uint(f);
  u += 0x7fffu + ((u >> 16) & 1u);
  return (unsigned short)(u >> 16);
}

// Convert f32 -> bf16 (vectorized), and compute sum of squares (for ||U||_F, ||V||_F)
__global__ void convert_kernel(const float* __restrict__ X, unsigned short* __restrict__ Xb,
                               double* __restrict__ partial, int n4) {
  int tid = blockIdx.x * blockDim.x + threadIdx.x;
  int stride = gridDim.x * blockDim.x;
  float s = 0.f;
  const float4* X4 = (const float4*)X;
  ushort4* Xb4 = (ushort4*)Xb;
  for (int i = tid; i < n4; i += stride) {
    float4 v = X4[i];
    s += v.x * v.x + v.y * v.y + v.z * v.z + v.w * v.w;
    ushort4 p;
    p.x = f32_to_bf16_rne(v.x);
    p.y = f32_to_bf16_rne(v.y);
    p.z = f32_to_bf16_rne(v.z);
    p.w = f32_to_bf16_rne(v.w);
    Xb4[i] = p;
  }
  // wave reduce (64-wide), then cross-wave via LDS
  for (int off = 32; off > 0; off >>= 1) s += __shfl_down(s, off, 64);
  __shared__ float sw[4];
  int lane = threadIdx.x & 63, wid = threadIdx.x >> 6;
  if (lane == 0) sw[wid] = s;
  __syncthreads();
  if (threadIdx.x == 0) partial[blockIdx.x] = (double)(sw[0] + sw[1] + sw[2] + sw[3]);
}

// Fused P = Xb * Yb^T (K=128, bf16 MFMA), then sum((P - T)^2) over the block's
// 128x128 tile. One double partial per block. No LDS staging: each lane's MFMA
// fragment is 8 contiguous bf16 in a row of Xb/Yb (L2-resident, ~3MB total).
__global__ __launch_bounds__(256) void fused_tile(
    const unsigned short* __restrict__ Xb,  // [rows][128] bf16 bits
    const unsigned short* __restrict__ Yb,  // [cols][128] bf16 bits
    const float* __restrict__ T,            // [rows][cols]
    double* __restrict__ partial,
    int ldT) {
  const int tid = threadIdx.x;
  const int lane = tid & 63;
  const int wid = tid >> 6;       // 4 waves: 2x2 arrangement of 64x64 sub-tiles
  const int wr = wid >> 1, wc = wid & 1;
  const int l15 = lane & 15;
  const int lg = lane >> 4;       // 0..3

  const int row0 = blockIdx.y * 128 + wr * 64;
  const int col0 = blockIdx.x * 128 + wc * 64;

  f32x4 acc[4][4] = {};

  const unsigned short* Arow = Xb + (row0 + l15) * KDIM + lg * 8;
  const unsigned short* Brow = Yb + (col0 + l15) * KDIM + lg * 8;

#pragma unroll
  for (int kk = 0; kk < 4; ++kk) {
    bf16x8 a[4], b[4];
#pragma unroll
    for (int m = 0; m < 4; ++m)
      a[m] = *(const bf16x8*)(Arow + m * 16 * KDIM + kk * 32);
#pragma unroll
    for (int n = 0; n < 4; ++n)
      b[n] = *(const bf16x8*)(Brow + n * 16 * KDIM + kk * 32);
#pragma unroll
    for (int m = 0; m < 4; ++m)
#pragma unroll
      for (int n = 0; n < 4; ++n)
        acc[m][n] = __builtin_amdgcn_mfma_f32_16x16x32_bf16(a[m], b[n], acc[m][n], 0, 0, 0);
  }

  // Epilogue: C/D layout col = lane&15, row = (lane>>4)*4 + j  [verified mapping]
  float s = 0.f;
#pragma unroll
  for (int m = 0; m < 4; ++m) {
    const int r = row0 + m * 16 + lg * 4;
#pragma unroll
    for (int n = 0; n < 4; ++n) {
      const int c = col0 + n * 16 + l15;
      const float* Tp = T + (size_t)r * ldT + c;
#pragma unroll
      for (int j = 0; j < 4; ++j) {
        float d = acc[m][n][j] - Tp[(size_t)j * ldT];
        s += d * d;
      }
    }
  }

  // deterministic block reduction
  for (int off = 32; off > 0; off >>= 1) s += __shfl_down(s, off, 64);
  __shared__ float sw[4];
  if (lane == 0) sw[wid] = s;
  __syncthreads();
  if (tid == 0)
    partial[blockIdx.y * gridDim.x + blockIdx.x] = (double)(sw[0] + sw[1] + sw[2] + sw[3]);
}

// Deterministic final reduction of all partial arrays + scalar combine.
__global__ void finalize_kernel(const double* __restrict__ pr, int nr,
                                const double* __restrict__ psm, int nsm,
                                const double* __restrict__ psd, int nsd,
                                const double* __restrict__ pu, int nu,
                                const double* __restrict__ pv, int nv,
                                float* __restrict__ out) {
  __shared__ double sh[256];
  double sums[5];
  const double* ps[5] = {pr, psm, psd, pu, pv};
  int ns[5] = {nr, nsm, nsd, nu, nv};
  for (int q = 0; q < 5; ++q) {
    double s = 0.0;
    for (int i = threadIdx.x; i < ns[q]; i += 256) s += ps[q][i];
    sh[threadIdx.x] = s;
    __syncthreads();
    for (int k = 128; k > 0; k >>= 1) {
      if (threadIdx.x < k) sh[threadIdx.x] += sh[threadIdx.x + k];
      __syncthreads();
    }
    sums[q] = sh[0];
    __syncthreads();
  }
  if (threadIdx.x == 0) {
    double recon = sums[0] / ((double)MDIM * (double)NDIM);
    double res = recon + 0.01 * (sqrt(sums[3]) + sqrt(sums[4]) + sqrt(sums[1]) + sqrt(sums[2]));
    out[0] = (float)res;
  }
}

extern "C" void kernel_launch(void* const* d_in, const int* in_sizes, int n_in,
                              void* d_out, int out_size, void* d_ws, size_t ws_size,
                              hipStream_t stream) {
  const float* A   = (const float*)d_in[0];  // [M][N]
  const float* S_m = (const float*)d_in[1];  // [M][M]
  const float* S_d = (const float*)d_in[2];  // [N][N]
  const float* U   = (const float*)d_in[3];  // [M][K]
  const float* V   = (const float*)d_in[4];  // [N][K]

  char* ws = (char*)d_ws;
  unsigned short* Ub = (unsigned short*)ws;                           // 2 MB
  unsigned short* Vb = (unsigned short*)(ws + (size_t)2 * 1024 * 1024); // 1 MB
  double* pd = (double*)(ws + (size_t)3 * 1024 * 1024);
  double* p_recon = pd;             // 2048 (64x32 blocks)
  double* p_sm    = p_recon + 2048; // 4096 (64x64)
  double* p_sd    = p_sm + 4096;    // 1024 (32x32)
  double* p_u     = p_sd + 1024;    // 256
  double* p_v     = p_u + 256;      // 256

  convert_kernel<<<256, 256, 0, stream>>>(U, Ub, p_u, MDIM * KDIM / 4);
  convert_kernel<<<256, 256, 0, stream>>>(V, Vb, p_v, NDIM * KDIM / 4);

  fused_tile<<<dim3(NDIM / 128, MDIM / 128), 256, 0, stream>>>(Ub, Vb, A, p_recon, NDIM);
  fused_tile<<<dim3(MDIM / 128, MDIM / 128), 256, 0, stream>>>(Ub, Ub, S_m, p_sm, MDIM);
  fused_tile<<<dim3(NDIM / 128, NDIM / 128), 256, 0, stream>>>(Vb, Vb, S_d, p_sd, NDIM);

  finalize_kernel<<<1, 256, 0, stream>>>(p_recon, 2048, p_sm, 4096, p_sd, 1024,
                                         p_u, 256, p_v, 256, (float*)d_out);
}